// Round 1
// 515.615 us; speedup vs baseline: 1.3594x; 1.3594x over previous
//
#include <hip/hip_runtime.h>
#include <stdint.h>

#define S_LEN 2048
#define NHEAD 16
#define DHEAD 64
#define DMODEL 1024
#define MROWS 8192  // B*S

typedef unsigned short ushort_t;
typedef __attribute__((ext_vector_type(8))) __bf16 bf16x8;
typedef __attribute__((ext_vector_type(4))) float f32x4;

__device__ __forceinline__ float bf2f(ushort_t h) {
    union { unsigned int u; float f; } v; v.u = ((unsigned int)h) << 16; return v.f;
}
__device__ __forceinline__ ushort_t f2bf(float f) {
    union { float f; unsigned int u; } v; v.f = f;
    unsigned int u = v.u + 0x7fffu + ((v.u >> 16) & 1u);  // round-to-nearest-even
    return (ushort_t)(u >> 16);
}

// Direct global->LDS 16B async copy (CK-style addrspace casts).
// LDS dest is wave-uniform base + lane*16; global src is per-lane.
__device__ __forceinline__ void gload_lds16(const void* g, void* l)
{
    auto* g1 = reinterpret_cast<const __attribute__((address_space(1))) void*>(
        reinterpret_cast<uintptr_t>(g));
    auto* l3 = reinterpret_cast<__attribute__((address_space(3))) void*>(
        reinterpret_cast<uintptr_t>(l));
    __builtin_amdgcn_global_load_lds(g1, l3, 16, 0, 0);
}

// ---------------------------------------------------------------------------
// Dtype detection (HW-verified round 4/6: query f32 -> flag=1).
// ---------------------------------------------------------------------------
__global__ void detect_dtype(const unsigned int* __restrict__ q, int* __restrict__ flag)
{
    __shared__ int cnt;
    if (threadIdx.x == 0) cnt = 0;
    __syncthreads();
    int c = 0;
    for (int i = 0; i < 8; ++i) {
        const unsigned int w = q[threadIdx.x * 8 + i];   // first 512 words
        const unsigned int lo = w & 0xffffu;
        const unsigned int e = (lo >> 7) & 0xffu;        // bf16 exponent field
        if (lo == 0u || (e >= 96u && e <= 160u)) ++c;    // "sane" bf16
    }
    atomicAdd(&cnt, c);
    __syncthreads();
    if (threadIdx.x == 0) flag[0] = (cnt < 400) ? 1 : 0;
}

// ---------------------------------------------------------------------------
// mask -> per 128x128 tile flag (1 = all nonzero -> skip elementwise path)
// ---------------------------------------------------------------------------
__global__ void mask_flags(const int* __restrict__ mask, int* __restrict__ flags)
{
    __shared__ int ok_s;
    if (threadIdx.x == 0) ok_s = 1;
    __syncthreads();
    const int t = blockIdx.x;            // 0..255
    const int tq = t >> 4, tk = t & 15;
    int ok = 1;
    for (int i = 0; i < 64; ++i) {
        const int idx = i * 256 + threadIdx.x;    // 0..16383
        const int r = idx >> 7, c = idx & 127;
        if (mask[(size_t)(tq * 128 + r) * S_LEN + tk * 128 + c] == 0) { ok = 0; break; }
    }
    if (!ok) atomicAnd(&ok_s, 0);
    __syncthreads();
    if (threadIdx.x == 0) flags[t] = ok_s;
}

__device__ __forceinline__ float loadscal(const void* b, int i, bool f32)
{
    return f32 ? ((const float*)b)[i] : bf2f(((const ushort_t*)b)[i]);
}

// ---------------------------------------------------------------------------
// One-shot dtype normalization: src (f32 or bf16, per dflag[fidx]) -> bf16.
// Memory-bound; vectorized 8 elems/thread/iter. Hoists the f32->bf16
// conversion out of the GEMM staging loop (was repeated 8x/64x per tile).
// ---------------------------------------------------------------------------
__global__ __launch_bounds__(256)
void conv_bf16(const void* __restrict__ src, ushort_t* __restrict__ dst,
               int n8, const int* __restrict__ dflag, int fidx)
{
    const bool f32 = dflag[fidx] != 0;
    const int stride = gridDim.x * 256;
    for (int i = blockIdx.x * 256 + threadIdx.x; i < n8; i += stride) {
        if (f32) {
            const float4 a = ((const float4*)src)[2 * (size_t)i];
            const float4 b = ((const float4*)src)[2 * (size_t)i + 1];
            union { ushort_t u[8]; uint4 v; } p;
            p.u[0] = f2bf(a.x); p.u[1] = f2bf(a.y); p.u[2] = f2bf(a.z); p.u[3] = f2bf(a.w);
            p.u[4] = f2bf(b.x); p.u[5] = f2bf(b.y); p.u[6] = f2bf(b.z); p.u[7] = f2bf(b.w);
            ((uint4*)dst)[i] = p.v;
        } else {
            ((uint4*)dst)[i] = ((const uint4*)src)[i];
        }
    }
}

// ---------------------------------------------------------------------------
// Pure-bf16 C = A @ W^T + bias, A:[8192,1024], W:[1024,1024] row-major bf16.
// m97 structure: 128x128 tile, BK=32, global_load_lds dwordx4 staging
// (linear LDS, stride 32, no pad -- required by wave-uniform LDS dest),
// 4 waves x 4x4 16x16x32 MFMA accumulators, 2-barrier K-loop.
// OUTF: true -> out f32, else bf16. bias dtype via dflag[1].
// ---------------------------------------------------------------------------
template <bool OUTF>
__global__ __launch_bounds__(256, 2)
void gemm_bf16(const ushort_t* __restrict__ A, const ushort_t* __restrict__ W,
               const void* __restrict__ bias, void* __restrict__ out,
               const int* __restrict__ dflag)
{
    constexpr int K = DMODEL, N = DMODEL;
    __shared__ ushort_t As[128 * 32];   // 8 KB, linear (stride 32 elems)
    __shared__ ushort_t Bs[128 * 32];   // 8 KB
    const bool bf32 = dflag[1] != 0;
    const int tid = threadIdx.x;
    const int lane = tid & 63;
    const int wave = tid >> 6;
    const int lrow = lane & 15, lq = lane >> 4;
    const int m0 = blockIdx.x * 128;
    const int n0 = blockIdx.y * 128;
    const int wr = (wave >> 1) * 64;
    const int wc = (wave & 1) * 64;

    const f32x4 zero4 = {0.f, 0.f, 0.f, 0.f};
    f32x4 acc[4][4];
#pragma unroll
    for (int i = 0; i < 4; ++i)
#pragma unroll
        for (int j = 0; j < 4; ++j) acc[i][j] = zero4;

    for (int k0 = 0; k0 < K; k0 += 32) {
        // Stage A,B tiles: 512 16B-chunks each, 2 issues/thread/matrix.
        // chunk c -> row c>>2, cols (c&3)*8; LDS linear => dest = chunk*16B.
#pragma unroll
        for (int i = 0; i < 2; ++i) {
            const int c = tid + i * 256;
            const int r = c >> 2, cc = (c & 3) * 8;
            const int lb = (wave * 64 + i * 256) * 8;   // wave-uniform lane-0 chunk
            gload_lds16(&A[(size_t)(m0 + r) * K + k0 + cc], &As[lb]);
            gload_lds16(&W[(size_t)(n0 + r) * K + k0 + cc], &Bs[lb]);
        }
        __syncthreads();   // compiler drains vmcnt before s_barrier
        bf16x8 af[4], bfr[4];
#pragma unroll
        for (int t = 0; t < 4; ++t) {
            af[t]  = *(const bf16x8*)(&As[(wr + t * 16 + lrow) * 32 + lq * 8]);
            bfr[t] = *(const bf16x8*)(&Bs[(wc + t * 16 + lrow) * 32 + lq * 8]);
        }
#pragma unroll
        for (int mt = 0; mt < 4; ++mt)
#pragma unroll
            for (int nt = 0; nt < 4; ++nt)
                acc[mt][nt] = __builtin_amdgcn_mfma_f32_16x16x32_bf16(
                    af[mt], bfr[nt], acc[mt][nt], 0, 0, 0);
        __syncthreads();
    }

#pragma unroll
    for (int nt = 0; nt < 4; ++nt) {
        const int n = n0 + wc + nt * 16 + lrow;
        const float bv = loadscal(bias, n, bf32);
#pragma unroll
        for (int mt = 0; mt < 4; ++mt) {
            const int mbase = m0 + wr + mt * 16 + lq * 4;
#pragma unroll
            for (int r = 0; r < 4; ++r) {
                const float v = acc[mt][nt][r] + bv;
                const size_t o = (size_t)(mbase + r) * N + n;
                if (OUTF) ((float*)out)[o] = v;
                else      ((ushort_t*)out)[o] = f2bf(v);
            }
        }
    }
}

// ---------------------------------------------------------------------------
// MFMA flash attention (unchanged this round). Q,K,V,X in [B*S,1024] bf16;
// head h = columns h*64..h*64+63. Grid (16 q-tiles, 64 bh), block 256.
// ---------------------------------------------------------------------------
__global__ __launch_bounds__(256, 2)
void attn_mfma(const ushort_t* __restrict__ Q, const ushort_t* __restrict__ K,
               const ushort_t* __restrict__ V, const int* __restrict__ mask,
               const int* __restrict__ flags, ushort_t* __restrict__ X)
{
    constexpr int KP = 72;    // K tile row stride
    constexpr int VP = 130;   // V^T tile row stride (even; bank-spread)
    constexpr int PP = 72;    // P tile row stride
    __shared__ ushort_t Ks[128 * KP];       // 18.0 KB
    __shared__ ushort_t VTs[64 * VP];       // 16.3 KB
    __shared__ ushort_t Ps[4][32 * PP];     // 18.0 KB (per-wave)

    const int tid = threadIdx.x;
    const int lane = tid & 63;
    const int wave = tid >> 6;
    const int lrow = lane & 15, lq = lane >> 4;
    const int bh = blockIdx.y, b = bh >> 4, h = bh & 15;
    const int q0 = blockIdx.x * 128;
    const int qw = q0 + wave * 32;
    const int coff = h * 64;
    const size_t rowb = (size_t)b * S_LEN;

    bf16x8 qf[2][2];
#pragma unroll
    for (int mt = 0; mt < 2; ++mt)
#pragma unroll
        for (int ks = 0; ks < 2; ++ks)
            qf[mt][ks] = *(const bf16x8*)(
                &Q[(rowb + qw + mt * 16 + lrow) * DMODEL + coff + ks * 32 + lq * 8]);

    const f32x4 zero4 = {0.f, 0.f, 0.f, 0.f};
    f32x4 o[2][4];
    float mr[2][4], lr[2][4];
#pragma unroll
    for (int mt = 0; mt < 2; ++mt) {
#pragma unroll
        for (int nt = 0; nt < 4; ++nt) o[mt][nt] = zero4;
#pragma unroll
        for (int r = 0; r < 4; ++r) { mr[mt][r] = -1e30f; lr[mt][r] = 0.f; }
    }

    ushort_t* const pw = &Ps[wave][0];

    for (int kt = 0; kt < 16; ++kt) {
        const int k0 = kt * 128;
#pragma unroll
        for (int i = 0; i < 4; ++i) {
            const int c = tid + i * 256;
            const int r = c >> 3, cc = (c & 7) * 8;
            *(uint4*)(&Ks[r * KP + cc]) =
                *(const uint4*)(&K[(rowb + k0 + r) * DMODEL + coff + cc]);
        }
#pragma unroll
        for (int i = 0; i < 2; ++i) {
            const int c = tid + i * 256;
            const int k2 = c >> 3;
            const int cc = (c & 7) * 8;
            union { uint4 v; ushort_t u[8]; } a, bb;
            a.v  = *(const uint4*)(&V[(rowb + k0 + 2 * k2)     * DMODEL + coff + cc]);
            bb.v = *(const uint4*)(&V[(rowb + k0 + 2 * k2 + 1) * DMODEL + coff + cc]);
#pragma unroll
            for (int j = 0; j < 8; ++j) {
                const unsigned int pk = (unsigned int)a.u[j] | ((unsigned int)bb.u[j] << 16);
                *(unsigned int*)(&VTs[(cc + j) * VP + 2 * k2]) = pk;
            }
        }
        __syncthreads();

        f32x4 s[2][8];
#pragma unroll
        for (int mt = 0; mt < 2; ++mt)
#pragma unroll
            for (int nt = 0; nt < 8; ++nt) s[mt][nt] = zero4;
#pragma unroll
        for (int nt = 0; nt < 8; ++nt) {
#pragma unroll
            for (int ks = 0; ks < 2; ++ks) {
                const bf16x8 kf = *(const bf16x8*)(&Ks[(nt * 16 + lrow) * KP + ks * 32 + lq * 8]);
                s[0][nt] = __builtin_amdgcn_mfma_f32_16x16x32_bf16(qf[0][ks], kf, s[0][nt], 0, 0, 0);
                s[1][nt] = __builtin_amdgcn_mfma_f32_16x16x32_bf16(qf[1][ks], kf, s[1][nt], 0, 0, 0);
            }
        }

#pragma unroll
        for (int mt = 0; mt < 2; ++mt)
#pragma unroll
            for (int nt = 0; nt < 8; ++nt)
#pragma unroll
                for (int r = 0; r < 4; ++r) s[mt][nt][r] *= 0.125f;
        if (!flags[blockIdx.x * 16 + kt]) {
            for (int mt = 0; mt < 2; ++mt)
                for (int nt = 0; nt < 8; ++nt)
                    for (int r = 0; r < 4; ++r) {
                        const int qi = qw + mt * 16 + lq * 4 + r;
                        const int ki = k0 + nt * 16 + lrow;
                        if (mask[(size_t)qi * S_LEN + ki] == 0) s[mt][nt][r] = -1e9f;
                    }
        }

#pragma unroll
        for (int mt = 0; mt < 2; ++mt) {
#pragma unroll
            for (int r = 0; r < 4; ++r) {
                float v = s[mt][0][r];
#pragma unroll
                for (int nt = 1; nt < 8; ++nt) v = fmaxf(v, s[mt][nt][r]);
#pragma unroll
                for (int off = 1; off < 16; off <<= 1) v = fmaxf(v, __shfl_xor(v, off, 64));
                const float mn = fmaxf(mr[mt][r], v);
                const float alpha = __expf(mr[mt][r] - mn);
                mr[mt][r] = mn;
                float rs = 0.f;
#pragma unroll
                for (int nt = 0; nt < 8; ++nt) {
                    const float p = __expf(s[mt][nt][r] - mn);
                    s[mt][nt][r] = p;
                    rs += p;
                }
#pragma unroll
                for (int off = 1; off < 16; off <<= 1) rs += __shfl_xor(rs, off, 64);
                lr[mt][r] = lr[mt][r] * alpha + rs;
#pragma unroll
                for (int nt = 0; nt < 4; ++nt) o[mt][nt][r] *= alpha;
            }
        }

#pragma unroll
        for (int half = 0; half < 2; ++half) {
#pragma unroll
            for (int mt = 0; mt < 2; ++mt)
#pragma unroll
                for (int nt = 0; nt < 4; ++nt)
#pragma unroll
                    for (int r = 0; r < 4; ++r)
                        pw[(mt * 16 + lq * 4 + r) * PP + nt * 16 + lrow] =
                            f2bf(s[mt][half * 4 + nt][r]);
#pragma unroll
            for (int ks = 0; ks < 2; ++ks) {
                const bf16x8 pf0 = *(const bf16x8*)(&pw[lrow * PP + ks * 32 + lq * 8]);
                const bf16x8 pf1 = *(const bf16x8*)(&pw[(16 + lrow) * PP + ks * 32 + lq * 8]);
                const int kb = half * 64 + ks * 32;
#pragma unroll
                for (int nt = 0; nt < 4; ++nt) {
                    const bf16x8 vf = *(const bf16x8*)(
                        &VTs[(nt * 16 + lrow) * VP + kb + lq * 8]);
                    o[0][nt] = __builtin_amdgcn_mfma_f32_16x16x32_bf16(pf0, vf, o[0][nt], 0, 0, 0);
                    o[1][nt] = __builtin_amdgcn_mfma_f32_16x16x32_bf16(pf1, vf, o[1][nt], 0, 0, 0);
                }
            }
        }
        __syncthreads();
    }

#pragma unroll
    for (int mt = 0; mt < 2; ++mt) {
#pragma unroll
        for (int r = 0; r < 4; ++r) {
            const float inv = 1.f / lr[mt][r];
            const int si = qw + mt * 16 + lq * 4 + r;
#pragma unroll
            for (int nt = 0; nt < 4; ++nt) {
                const int dk = nt * 16 + lrow;
                X[(rowb + si) * DMODEL + coff + dk] = f2bf(o[mt][nt][r] * inv);
            }
        }
    }
}

// ---------------------------------------------------------------------------
// Buffer choreography (zero extra workspace vs round 6's 48 MiB):
//   ws:    [Kp 16MiB][Vp 16MiB][Xp 16MiB][dflag 8B][flags 1KB]
//   d_out: [Qp bf16 16MiB][Ac bf16 16MiB]  (Ac = activation conv scratch)
//   Converted weights parked in dead regions:
//     Wq_c,Wk_c -> Vp[0..4MiB)   (Vp written only at step "gemm V")
//     Wv_c      -> Xp[0..2MiB)   (Xp written only by attn)
//     Wo_c      -> Vp[0..2MiB)   (reconverted after attn frees Vp)
// ---------------------------------------------------------------------------
extern "C" void kernel_launch(void* const* d_in, const int* in_sizes, int n_in,
                              void* d_out, int out_size, void* d_ws, size_t ws_size,
                              hipStream_t stream)
{
    const void* query = d_in[0];
    const void* key   = d_in[1];
    const void* value = d_in[2];
    const int*  mask  = (const int*)d_in[3];
    const void* w_q = d_in[4];
    const void* b_q = d_in[5];
    const void* w_k = d_in[6];
    const void* b_k = d_in[7];
    const void* w_v = d_in[8];
    const void* b_v = d_in[9];
    const void* w_o = d_in[10];
    const void* b_o = d_in[11];

    const size_t TEN = (size_t)MROWS * DMODEL;   // 8M elements
    ushort_t* Kp = (ushort_t*)d_ws;
    ushort_t* Vp = Kp + TEN;
    ushort_t* Xp = Vp + TEN;
    int* dflag   = (int*)(Xp + TEN);             // [0]=act f32, [1]=weights f32
    int* flags   = dflag + 2;                    // 256 tile flags
    ushort_t* Qp = (ushort_t*)d_out;             // d_out low half
    ushort_t* Ac = Qp + TEN;                     // d_out high half (conv scratch)
    ushort_t* Wq_c = Vp;
    ushort_t* Wk_c = Vp + (size_t)DMODEL * DMODEL;
    ushort_t* Wv_c = Xp;
    ushort_t* Wo_c = Vp;

    const int WN8 = DMODEL * DMODEL / 8;         // 131072
    const int AN8 = (int)(TEN / 8);              // 1048576

    detect_dtype<<<1, 64, 0, stream>>>((const unsigned int*)query, dflag + 0);
    detect_dtype<<<1, 64, 0, stream>>>((const unsigned int*)w_q,   dflag + 1);
    mask_flags<<<256, 256, 0, stream>>>(mask, flags);

    conv_bf16<<<512, 256, 0, stream>>>(w_q, Wq_c, WN8, dflag, 1);
    conv_bf16<<<512, 256, 0, stream>>>(w_k, Wk_c, WN8, dflag, 1);
    conv_bf16<<<512, 256, 0, stream>>>(w_v, Wv_c, WN8, dflag, 1);

    const dim3 gg(64, 8);
    conv_bf16<<<2048, 256, 0, stream>>>(query, Ac, AN8, dflag, 0);
    gemm_bf16<false><<<gg, 256, 0, stream>>>(Ac, Wq_c, b_q, Qp, dflag);
    conv_bf16<<<2048, 256, 0, stream>>>(key, Ac, AN8, dflag, 0);
    gemm_bf16<false><<<gg, 256, 0, stream>>>(Ac, Wk_c, b_k, Kp, dflag);
    conv_bf16<<<2048, 256, 0, stream>>>(value, Ac, AN8, dflag, 0);
    gemm_bf16<false><<<gg, 256, 0, stream>>>(Ac, Wv_c, b_v, Vp, dflag);

    attn_mfma<<<dim3(16, 64), 256, 0, stream>>>(Qp, Kp, Vp, mask, flags, Xp);

    conv_bf16<<<512, 256, 0, stream>>>(w_o, Wo_c, WN8, dflag, 1);
    gemm_bf16<true><<<gg, 256, 0, stream>>>(Xp, Wo_c, b_o, d_out, dflag);
}